// Round 17
// baseline (505.897 us; speedup 1.0000x reference)
//
#include <hip/hip_runtime.h>
#include <hip/hip_bf16.h>

typedef __bf16 bf16_t;
typedef float  f32x4  __attribute__((ext_vector_type(4)));
typedef bf16_t bf16x2 __attribute__((ext_vector_type(2)));
typedef bf16_t bf16x4 __attribute__((ext_vector_type(4)));
typedef bf16_t bf16x8 __attribute__((ext_vector_type(8)));

#define MFMA16(a, b, c) __builtin_amdgcn_mfma_f32_16x16x32_bf16((a), (b), (c), 0, 0, 0)

#define GLOAD_LDS16(g, l)                                                              \
  __builtin_amdgcn_global_load_lds((const __attribute__((address_space(1))) void*)(g), \
                                   (__attribute__((address_space(3))) void*)(l), 16, 0, 0)

#define BARRIER    __builtin_amdgcn_s_barrier()
#define WAIT_LGKM0 asm volatile("s_waitcnt lgkmcnt(0)" ::: "memory")
#define WAIT_LGKM8 asm volatile("s_waitcnt lgkmcnt(8)" ::: "memory")
#define WAIT_VM3   asm volatile("s_waitcnt vmcnt(3)" ::: "memory")
#define WAIT_VM4   asm volatile("s_waitcnt vmcnt(4)" ::: "memory")
#define WAIT_VM0   asm volatile("s_waitcnt vmcnt(0)" ::: "memory")

// ------- fused prep: 4 weight transposes + X f32->bf16 convert (one launch) -------
__global__ __launch_bounds__(256) void prep_all(const float* __restrict__ Wq,
                                                const float* __restrict__ Wk,
                                                const float* __restrict__ Wv,
                                                const float* __restrict__ Wo,
                                                const float* __restrict__ X,
                                                bf16_t* __restrict__ WqkvT,
                                                bf16_t* __restrict__ WoT,
                                                bf16_t* __restrict__ Xbf,
                                                int n4) {
  const int bid = blockIdx.x;
  if (bid >= 10240) {
    int stride = 2048 * 256;
    for (int i = (bid - 10240) * 256 + threadIdx.x; i < n4; i += stride) {
      f32x4 v = ((const f32x4*)X)[i];
      bf16x4 o;
#pragma unroll
      for (int j = 0; j < 4; ++j) o[j] = (bf16_t)v[j];
      ((bf16x4*)Xbf)[i] = o;
    }
    return;
  }
  __shared__ float t[64][65];
  const float* in;
  bf16_t* out;
  int C, cx, cy;
  if (bid < 4096) {
    in = Wq; out = WqkvT; C = 4096; cx = bid & 63; cy = bid >> 6;
  } else if (bid < 5120) {
    int tt = bid - 4096;
    in = Wk; out = WqkvT + 4096ull * 4096; C = 1024; cx = tt & 15; cy = tt >> 4;
  } else if (bid < 6144) {
    int tt = bid - 5120;
    in = Wv; out = WqkvT + 5120ull * 4096; C = 1024; cx = tt & 15; cy = tt >> 4;
  } else {
    int tt = bid - 6144;
    in = Wo; out = WoT; C = 4096; cx = tt & 63; cy = tt >> 6;
  }
  const int R = 4096;  // K dim (output stride)
  int tr0 = cy * 64, tc0 = cx * 64;
  int tx = threadIdx.x & 15, ty = threadIdx.x >> 4;
#pragma unroll
  for (int i = 0; i < 4; ++i) {
    f32x4 v = *(const f32x4*)(in + (size_t)(tr0 + ty + 16 * i) * C + tc0 + tx * 4);
#pragma unroll
    for (int j = 0; j < 4; ++j) t[ty + 16 * i][tx * 4 + j] = v[j];
  }
  __syncthreads();
#pragma unroll
  for (int i = 0; i < 4; ++i) {
    bf16x4 o4;
#pragma unroll
    for (int j = 0; j < 4; ++j) o4[j] = (bf16_t)t[tx * 4 + j][ty + 16 * i];
    *(bf16x4*)(out + (size_t)(tc0 + ty + 16 * i) * R + tr0 + tx * 4) = o4;
  }
}

// ================= 256x256 8-phase GEMM, 16x16x32 (O-projection) =================
// XCD 2-D supertile: 8 chunks of 4m x 8n (grid 16x16).
#define LDB8(bf)                                                                         \
  {                                                                                      \
    const int sb_ = bBase0 + (bf)*16384;                                                 \
    _Pragma("unroll") for (int nf = 0; nf < 4; ++nf) {                                   \
      int row_ = brow0 + nf * 16 + ci;                                                   \
      _Pragma("unroll") for (int ks = 0; ks < 2; ++ks)                                   \
          b[nf][ks] = *(const bf16x8*)&lds[sb_ + row_ * 64 + ((ks * 32 + g * 8) ^ co)];  \
    }                                                                                    \
  }

#define LDA4(bf, q)                                                                      \
  {                                                                                      \
    const int sb_ = aBase0 + (bf)*16384;                                                 \
    _Pragma("unroll") for (int j = 0; j < 2; ++j) {                                      \
      int row_ = ((q)*2 + j) * 16 + ci;                                                  \
      _Pragma("unroll") for (int ks = 0; ks < 2; ++ks)                                   \
          a[j][ks] = *(const bf16x8*)&lds[sb_ + row_ * 64 + ((ks * 32 + g * 8) ^ co)];   \
    }                                                                                    \
  }

#define MMQ(q)                                                                           \
  {                                                                                      \
    __builtin_amdgcn_s_setprio(1);                                                       \
    _Pragma("unroll") for (int j = 0; j < 2; ++j)                                        \
        _Pragma("unroll") for (int nf = 0; nf < 4; ++nf)                                 \
            _Pragma("unroll") for (int ks = 0; ks < 2; ++ks)                             \
                acc[(q)*2 + j][nf] = MFMA16(a[j][ks], b[nf][ks], acc[(q)*2 + j][nf]);    \
    __builtin_amdgcn_s_setprio(0);                                                       \
  }

template <int WRITE_BF16>
__global__ __launch_bounds__(512) void gemm8o(const bf16_t* __restrict__ A,
                                              const bf16_t* __restrict__ Bt,
                                              void* __restrict__ Cv,
                                              int N, int K) {
  __shared__ alignas(16) bf16_t lds[65536];  // A: [0,32768), B: [32768,65536)
  const int tid = threadIdx.x;
  const int lane = tid & 63, w = tid >> 6;
  const int wr = w >> 2, wc = w & 3;  // 2 M-waves x 4 N-waves
  const int g = lane >> 4, ci = lane & 15;
  const int c = (int)blockIdx.x & 7, ii = (int)blockIdx.x >> 3;
  const int m0 = ((c >> 1) * 4 + (ii >> 3)) * 256;
  const int n0 = ((c & 1) * 8 + (ii & 7)) * 256;
  const int ksw = ((lane & 7) ^ (lane >> 3)) << 3;
  const int aBase0 = wr * 8192;
  const int bBase0 = 32768 + (wc >> 1) * 8192;
  const int brow0 = (wc & 1) * 64;
  const int co = (ci & 7) << 3;

  const bf16_t* As[2] = {A + (size_t)m0 * K, A + (size_t)(m0 + 128) * K};
  const bf16_t* Bs[2] = {Bt + (size_t)n0 * K, Bt + (size_t)(n0 + 128) * K};

  auto stage = [&](const bf16_t* src, int kk, int ldsbase) {  // 128 rows x 64 k
#pragma unroll
    for (int j = 0; j < 2; ++j)
      GLOAD_LDS16(src + (size_t)(j * 64 + w * 8 + (lane >> 3)) * K + kk + ksw,
                  (char*)&lds[ldsbase + (j * 64 + w * 8) * 64]);
  };

  bf16x8 a[2][2], b[4][2];
  f32x4 acc[8][4];
#pragma unroll
  for (int mf = 0; mf < 8; ++mf)
#pragma unroll
    for (int nf = 0; nf < 4; ++nf) acc[mf][nf] = f32x4{0.f, 0.f, 0.f, 0.f};

  stage(As[0], 0, 0);
  stage(As[1], 0, 8192);
  stage(Bs[0], 0, 32768);
  stage(Bs[1], 0, 40960);
  stage(Bs[0], 64, 49152);
  stage(Bs[1], 64, 57344);
  WAIT_VM4;
  BARRIER;

  const int NT2 = K >> 7;
  for (int i = 0; i < NT2; ++i) {
    const int keb = i << 7;
    const int kA1 = keb + 64;
    int e2 = keb + 128;
    if (e2 > K - 64) e2 = K - 64;
    int o2 = keb + 192;
    if (o2 > K - 64) o2 = K - 64;
    LDA4(0, 0) LDB8(0)
    stage(As[0], kA1, 16384);
    WAIT_LGKM8;
    BARRIER; WAIT_LGKM0;
    MMQ(0)
    BARRIER;
    LDA4(0, 1)
    stage(As[1], kA1, 24576);
    BARRIER; WAIT_LGKM0;
    MMQ(1)
    BARRIER;
    LDA4(0, 2)
    stage(Bs[0], e2, 32768);
    BARRIER; WAIT_LGKM0;
    MMQ(2)
    BARRIER;
    LDA4(0, 3)
    stage(Bs[1], e2, 40960);
    BARRIER; WAIT_LGKM0;
    MMQ(3)
    WAIT_VM4;
    BARRIER;
    LDA4(1, 0) LDB8(1)
    stage(As[0], e2, 0);
    WAIT_LGKM8;
    BARRIER; WAIT_LGKM0;
    MMQ(0)
    BARRIER;
    LDA4(1, 1)
    stage(As[1], e2, 8192);
    BARRIER; WAIT_LGKM0;
    MMQ(1)
    BARRIER;
    LDA4(1, 2)
    stage(Bs[0], o2, 49152);
    BARRIER; WAIT_LGKM0;
    MMQ(2)
    BARRIER;
    LDA4(1, 3)
    stage(Bs[1], o2, 57344);
    BARRIER; WAIT_LGKM0;
    MMQ(3)
    WAIT_VM4;
    BARRIER;
  }
  WAIT_VM0;

#pragma unroll
  for (int mf = 0; mf < 8; ++mf) {
#pragma unroll
    for (int nf = 0; nf < 4; ++nf) {
      int grow = m0 + wr * 128 + mf * 16 + g * 4;
      int gcol = n0 + wc * 64 + nf * 16 + ci;
#pragma unroll
      for (int r = 0; r < 4; ++r) {
        if (WRITE_BF16)
          ((bf16_t*)Cv)[(size_t)(grow + r) * N + gcol] = (bf16_t)acc[mf][nf][r];
        else
          ((float*)Cv)[(size_t)(grow + r) * N + gcol] = acc[mf][nf][r];
      }
    }
  }
}

// ================= 256x192 8-phase GEMM, 16x16x32 (QKV) =================
// XCD 2-D supertile: 8 chunks of 8m x 8n (grid 16x32).
#define QLDB12(bf)                                                                        \
  {                                                                                       \
    const int sb_ = 32768 + (bf)*12288;                                                   \
    _Pragma("unroll") for (int nf = 0; nf < 6; ++nf) {                                    \
      int row_ = wc * 96 + nf * 16 + ci;                                                  \
      _Pragma("unroll") for (int ks = 0; ks < 2; ++ks)                                    \
          b[nf][ks] = *(const bf16x8*)&lds[sb_ + row_ * 64 + ((ks * 32 + g * 8) ^ co)];   \
    }                                                                                     \
  }

#define QLDA2(bf, q)                                                                      \
  {                                                                                       \
    const int sb_ = (bf)*16384;                                                           \
    const int row_ = wr * 64 + (q)*16 + ci;                                               \
    _Pragma("unroll") for (int ks = 0; ks < 2; ++ks)                                      \
        a[ks] = *(const bf16x8*)&lds[sb_ + row_ * 64 + ((ks * 32 + g * 8) ^ co)];         \
  }

#define QMMQ(q)                                                                           \
  {                                                                                       \
    __builtin_amdgcn_s_setprio(1);                                                        \
    _Pragma("unroll") for (int nf = 0; nf < 6; ++nf)                                      \
        _Pragma("unroll") for (int ks = 0; ks < 2; ++ks)                                  \
            acc[q][nf] = MFMA16(a[ks], b[nf][ks], acc[q][nf]);                            \
    __builtin_amdgcn_s_setprio(0);                                                        \
  }

__global__ __launch_bounds__(512) void gemm8qkv(const bf16_t* __restrict__ A,
                                                const bf16_t* __restrict__ Bt,
                                                bf16_t* __restrict__ C,
                                                int N, int K) {
  __shared__ alignas(16) bf16_t lds[57344];
  const int tid = threadIdx.x;
  const int lane = tid & 63, w = tid >> 6;
  const int wr = w >> 1, wc = w & 1;  // 4 M-waves x 2 N-waves
  const int g = lane >> 4, ci = lane & 15;
  const int c = (int)blockIdx.x & 7, ii = (int)blockIdx.x >> 3;
  const int m0 = ((c >> 2) * 8 + (ii >> 3)) * 256;
  const int n0 = ((c & 3) * 8 + (ii & 7)) * 192;
  const int ksw = ((lane & 7) ^ (lane >> 3)) << 3;
  const int co = (ci & 7) << 3;

  const bf16_t* Ar[4] = {A + (size_t)m0 * K, A + (size_t)(m0 + 64) * K,
                         A + (size_t)(m0 + 128) * K, A + (size_t)(m0 + 192) * K};
  const bf16_t* Br[3] = {Bt + (size_t)n0 * K, Bt + (size_t)(n0 + 64) * K,
                         Bt + (size_t)(n0 + 128) * K};

  auto stage64 = [&](const bf16_t* src, int kk, int ldsbase) {  // 64 rows x 64 k
    GLOAD_LDS16(src + (size_t)(w * 8 + (lane >> 3)) * K + kk + ksw,
                (char*)&lds[ldsbase + w * 512]);
  };

  bf16x8 a[2], b[6][2];
  f32x4 acc[4][6];
#pragma unroll
  for (int mf = 0; mf < 4; ++mf)
#pragma unroll
    for (int nf = 0; nf < 6; ++nf) acc[mf][nf] = f32x4{0.f, 0.f, 0.f, 0.f};

#pragma unroll
  for (int c2 = 0; c2 < 4; ++c2) stage64(Ar[c2], 0, c2 * 4096);
#pragma unroll
  for (int c2 = 0; c2 < 3; ++c2) stage64(Br[c2], 0, 32768 + c2 * 4096);
#pragma unroll
  for (int c2 = 0; c2 < 3; ++c2) stage64(Br[c2], 64, 45056 + c2 * 4096);
  WAIT_VM3;
  BARRIER;

  const int NT2 = K >> 7;
  for (int i = 0; i < NT2; ++i) {
    const int keb = i << 7;
    const int kA1 = keb + 64;
    int e2 = keb + 128;
    if (e2 > K - 64) e2 = K - 64;
    int o2 = keb + 192;
    if (o2 > K - 64) o2 = K - 64;
    QLDA2(0, 0) QLDB12(0)
    stage64(Ar[0], kA1, 16384);
    stage64(Ar[1], kA1, 16384 + 4096);
    WAIT_LGKM8;
    BARRIER; WAIT_LGKM0;
    QMMQ(0)
    BARRIER;
    QLDA2(0, 1)
    stage64(Ar[2], kA1, 16384 + 8192);
    stage64(Ar[3], kA1, 16384 + 12288);
    BARRIER; WAIT_LGKM0;
    QMMQ(1)
    BARRIER;
    QLDA2(0, 2)
    stage64(Br[0], e2, 32768);
    stage64(Br[1], e2, 32768 + 4096);
    BARRIER; WAIT_LGKM0;
    QMMQ(2)
    BARRIER;
    QLDA2(0, 3)
    stage64(Br[2], e2, 32768 + 8192);
    BARRIER; WAIT_LGKM0;
    QMMQ(3)
    WAIT_VM3;
    BARRIER;
    QLDA2(1, 0) QLDB12(1)
    stage64(Ar[0], e2, 0);
    stage64(Ar[1], e2, 4096);
    WAIT_LGKM8;
    BARRIER; WAIT_LGKM0;
    QMMQ(0)
    BARRIER;
    QLDA2(1, 1)
    stage64(Ar[2], e2, 8192);
    stage64(Ar[3], e2, 12288);
    BARRIER; WAIT_LGKM0;
    QMMQ(1)
    BARRIER;
    QLDA2(1, 2)
    stage64(Br[0], o2, 45056);
    stage64(Br[1], o2, 45056 + 4096);
    BARRIER; WAIT_LGKM0;
    QMMQ(2)
    BARRIER;
    QLDA2(1, 3)
    stage64(Br[2], o2, 45056 + 8192);
    BARRIER; WAIT_LGKM0;
    QMMQ(3)
    WAIT_VM3;
    BARRIER;
  }
  WAIT_VM0;

#pragma unroll
  for (int mf = 0; mf < 4; ++mf) {
#pragma unroll
    for (int nf = 0; nf < 6; ++nf) {
      int grow = m0 + wr * 64 + mf * 16 + g * 4;
      int gcol = n0 + wc * 96 + nf * 16 + ci;
#pragma unroll
      for (int r = 0; r < 4; ++r)
        C[(size_t)(grow + r) * N + gcol] = (bf16_t)acc[mf][nf][r];
    }
  }
}

// ------------- RoPE K + pack V: QKV [token][6144] -> Kr, Vr [B,KVH,N,D] -------------
__global__ __launch_bounds__(256) void rope_kv(const bf16_t* __restrict__ QKV,
                                               const int* __restrict__ pos,
                                               bf16_t* __restrict__ Kr,
                                               bf16_t* __restrict__ Vr) {
  int unit = blockIdx.x * 8 + (threadIdx.x >> 5);  // token*8 + kvh
  int l = threadIdx.x & 31;
  int token = unit >> 3, kvh = unit & 7;
  int b = token >> 11, n = token & 2047;
  const bf16_t* base = QKV + (size_t)token * 6144;
  // K rope
  {
    const bf16_t* src = base + 4096 + kvh * 128;
    bf16_t* dst = Kr + ((size_t)(b * 8 + kvh) * 2048 + n) * 128;
    float p = (float)pos[token];
    float a0 = p * exp2f(-(float)(2 * l) * 0.20762050593045702f);
    float a1 = p * exp2f(-(float)(2 * l + 1) * 0.20762050593045702f);
    float sn0, cs0, sn1, cs1;
    sincosf(a0, &sn0, &cs0);
    sincosf(a1, &sn1, &cs1);
    bf16x2 x0 = *(const bf16x2*)(src + 2 * l);
    bf16x2 x1 = *(const bf16x2*)(src + 64 + 2 * l);
    bf16x2 o0, o1;
    o0[0] = (bf16_t)((float)x0[0] * cs0 - (float)x1[0] * sn0);
    o0[1] = (bf16_t)((float)x0[1] * cs1 - (float)x1[1] * sn1);
    o1[0] = (bf16_t)((float)x1[0] * cs0 + (float)x0[0] * sn0);
    o1[1] = (bf16_t)((float)x1[1] * cs1 + (float)x0[1] * sn1);
    *(bf16x2*)(dst + 2 * l) = o0;
    *(bf16x2*)(dst + 64 + 2 * l) = o1;
  }
  // V pack
  {
    const bf16_t* src = base + 5120 + kvh * 128;
    bf16_t* dst = Vr + ((size_t)(b * 8 + kvh) * 2048 + n) * 128;
    *(bf16x4*)(dst + 4 * l) = *(const bf16x4*)(src + 4 * l);
  }
}

// -------- flash attention: r16 skeleton + 48KB LDS (Pl qb-sequential 16-row) --------
__global__ __launch_bounds__(512) void attn_kernel(const bf16_t* __restrict__ QKV,
                                                   const bf16_t* __restrict__ K,
                                                   const bf16_t* __restrict__ V,
                                                   const int* __restrict__ pos,
                                                   bf16_t* __restrict__ O) {
  const float scale2 = 0.12751743f;  // (1/sqrt(128)) * log2(e)
  __shared__ alignas(16) bf16_t Kl[64 * 128];    // swizzled [kv][d] (16K)
  __shared__ alignas(16) bf16_t Vt[128 * 64];    // swizzled [d][kv] (16K)
  __shared__ alignas(16) bf16_t Pl[8][16 * 64];  // per-wave 16-row P buffer (16K)
  const int tid = threadIdx.x;
  const int lane = tid & 63, w = tid >> 6;
  const int g = lane >> 4, ci = lane & 15;
  const int hb = blockIdx.y;  // b*32 + h
  const int b = hb >> 5, h = hb & 31, kvh = h >> 2;
  const int p = blockIdx.x;  // pair index 0..7
  const int qtB = 15 - p;
  const int qr[2] = {p * 128 + w * 16, qtB * 128 + w * 16};
  const bf16_t* Kh = K + (size_t)(b * 8 + kvh) * 2048 * 128;
  const bf16_t* Vh = V + (size_t)(b * 8 + kvh) * 2048 * 128;

  // Q load + in-register RoPE + pre-scale by scale2 (once per block)
  bf16x8 bq[2][4];
#pragma unroll
  for (int qb = 0; qb < 2; ++qb) {
    const int n = qr[qb] + ci;
    const bf16_t* qp = QKV + (size_t)(b * 2048 + n) * 6144 + h * 128;
    bf16x8 raw[4];
#pragma unroll
    for (int ks = 0; ks < 4; ++ks) raw[ks] = *(const bf16x8*)(qp + ks * 32 + g * 8);
    float ppos = (float)pos[b * 2048 + n];
#pragma unroll
    for (int k2 = 0; k2 < 2; ++k2)
#pragma unroll
      for (int j = 0; j < 8; ++j) {
        int d = k2 * 32 + g * 8 + j;
        float ang = ppos * exp2f(-(float)d * 0.20762050593045702f);
        float sn, cs;
        sincosf(ang, &sn, &cs);
        float x0 = (float)raw[k2][j], x1 = (float)raw[k2 + 2][j];
        bq[qb][k2][j] = (bf16_t)((x0 * cs - x1 * sn) * scale2);
        bq[qb][k2 + 2][j] = (bf16_t)((x1 * cs + x0 * sn) * scale2);
      }
  }

  f32x4 o[2][8];
#pragma unroll
  for (int qb = 0; qb < 2; ++qb)
#pragma unroll
    for (int nb = 0; nb < 8; ++nb) o[qb][nb] = f32x4{0.f, 0.f, 0.f, 0.f};
  float mrow[2] = {-1e30f, -1e30f};
  float lrow[2] = {0.f, 0.f};

  // T14 reg-staged K/V
  bf16x8 kreg[2];
  bf16x4 rv[4];
  const int kq = tid >> 5, dq = tid & 31;
  auto loadKV = [&](int kv0) {
#pragma unroll
    for (int i = 0; i < 2; ++i) {
      int c = tid + i * 512;
      kreg[i] = *(const bf16x8*)(Kh + (size_t)(kv0 + (c >> 4)) * 128 + (c & 15) * 8);
    }
#pragma unroll
    for (int rr = 0; rr < 4; ++rr)
      rv[rr] = *(const bf16x4*)(Vh + (size_t)(kv0 + kq * 4 + rr) * 128 + dq * 4);
  };
  auto writeKV = [&]() {
#pragma unroll
    for (int i = 0; i < 2; ++i) {
      int c = tid + i * 512;
      int row = c >> 4, kc = (c & 15) * 8;
      int sw = ((row ^ (row >> 3)) & 7) << 4;
      *(bf16x8*)((char*)Kl + row * 256 + ((kc * 2) ^ sw)) = kreg[i];
    }
#pragma unroll
    for (int jj = 0; jj < 4; ++jj) {
      int d = dq * 4 + jj;
      bf16x4 cv;
#pragma unroll
      for (int rr = 0; rr < 4; ++rr) cv[rr] = rv[rr][jj];
      int sw = ((d ^ (d >> 3)) & 7) << 4;
      *(bf16x4*)((char*)Vt + d * 128 + ((kq * 8) ^ sw)) = cv;
    }
  };

  const int nt = (qtB + 1) * 2;
  const int swp = ((ci ^ (ci >> 3)) & 7) << 4;  // Pl row = ci
  loadKV(0);
  for (int t = 0; t < nt; ++t) {
    const int kv0 = t * 64;
    __syncthreads();
    writeKV();
    __syncthreads();
    if (t + 1 < nt) loadKV(kv0 + 64);

    bool act[2] = {kv0 <= qr[0] + 15, kv0 <= qr[1] + 15};
    bf16x8 pa[2][2];
#pragma unroll
    for (int qb = 0; qb < 2; ++qb) {
      if (!act[qb]) continue;
      f32x4 st[4];
#pragma unroll
      for (int kvb = 0; kvb < 4; ++kvb) st[kvb] = f32x4{0.f, 0.f, 0.f, 0.f};
      __builtin_amdgcn_s_setprio(1);
#pragma unroll
      for (int kvb = 0; kvb < 4; ++kvb) {
        int row = kvb * 16 + ci;
        int sw = ((row ^ (row >> 3)) & 7) << 4;
#pragma unroll
        for (int ks = 0; ks < 4; ++ks) {
          bf16x8 ak = *(const bf16x8*)((char*)Kl + row * 256 + ((ks * 64 + g * 16) ^ sw));
          st[kvb] = MFMA16(ak, bq[qb][ks], st[kvb]);
        }
      }
      __builtin_amdgcn_s_setprio(0);
      const int q = qr[qb] + ci;
      float pm = -1e30f;
      if (kv0 + 63 > qr[qb]) {  // diagonal tile: causal mask (wave-uniform branch)
#pragma unroll
        for (int kvb = 0; kvb < 4; ++kvb)
#pragma unroll
          for (int r = 0; r < 4; ++r) {
            float v = st[kvb][r];  // Q pre-scaled
            if (kv0 + kvb * 16 + 4 * g + r > q) v = -1e30f;
            st[kvb][r] = v;
            pm = fmaxf(pm, v);
          }
      } else {
#pragma unroll
        for (int kvb = 0; kvb < 4; ++kvb)
#pragma unroll
          for (int r = 0; r < 4; ++r) pm = fmaxf(pm, st[kvb][r]);
      }
      pm = fmaxf(pm, __shfl_xor(pm, 16));
      pm = fmaxf(pm, __shfl_xor(pm, 32));
      // T13 defer-max (log2 domain threshold ~ 8*log2e)
      const bool nskip = !__all((int)(pm <= mrow[qb] + 11.5f));
      const float mold = mrow[qb];
      float mnew = mold;
      float fs = 1.0f;
      if (nskip) {
        mnew = fmaxf(mold, pm);
        fs = exp2f(mold - mnew);
        mrow[qb] = mnew;
      }
      float ps = 0.f;
#pragma unroll
      for (int kvb = 0; kvb < 4; ++kvb)
#pragma unroll
        for (int r = 0; r < 4; ++r) {
          st[kvb][r] = exp2f(st[kvb][r] - mnew);
          ps += st[kvb][r];
        }
      ps += __shfl_xor(ps, 16);
      ps += __shfl_xor(ps, 32);
      lrow[qb] = (nskip ? lrow[qb] * fs : lrow[qb]) + ps;
      // P -> Pl (16-row qb-sequential reuse), then read pa immediately (same-wave
      // DS ordering; pa regs filled before qb=1 overwrites — r10/r13-proven)
#pragma unroll
      for (int kvb = 0; kvb < 4; ++kvb) {
        bf16x4 pk;
#pragma unroll
        for (int r = 0; r < 4; ++r) pk[r] = (bf16_t)st[kvb][r];
        *(bf16x4*)((char*)&Pl[w][0] + ci * 128 + (((kvb * 16 + 4 * g) * 2) ^ swp)) = pk;
      }
#pragma unroll
      for (int ks = 0; ks < 2; ++ks)
        pa[qb][ks] = *(const bf16x8*)((char*)&Pl[w][0] + ci * 128 + ((ks * 64 + g * 16) ^ swp));
      if (nskip) {
        float fo[4];
#pragma unroll
        for (int r = 0; r < 4; ++r) fo[r] = __shfl(fs, 4 * g + r);
#pragma unroll
        for (int nb = 0; nb < 8; ++nb)
#pragma unroll
          for (int r = 0; r < 4; ++r) o[qb][nb][r] *= fo[r];
      }
    }
    __builtin_amdgcn_s_setprio(1);
#pragma unroll
    for (int nb = 0; nb < 8; ++nb) {
      int d = nb * 16 + ci;
      int sw = ((d ^ (d >> 3)) & 7) << 4;
      bf16x8 bv0 = *(const bf16x8*)((char*)Vt + d * 128 + ((g * 16) ^ sw));
      bf16x8 bv1 = *(const bf16x8*)((char*)Vt + d * 128 + ((64 + g * 16) ^ sw));
#pragma unroll
      for (int qb = 0; qb < 2; ++qb) {
        if (!act[qb]) continue;
        o[qb][nb] = MFMA16(pa[qb][0], bv0, o[qb][nb]);
        o[qb][nb] = MFMA16(pa[qb][1], bv1, o[qb][nb]);
      }
    }
    __builtin_amdgcn_s_setprio(0);
  }
#pragma unroll
  for (int qb = 0; qb < 2; ++qb) {
    float linv = 1.0f / lrow[qb];
    float lv[4];
#pragma unroll
    for (int r = 0; r < 4; ++r) lv[r] = __shfl(linv, 4 * g + r);
#pragma unroll
    for (int r = 0; r < 4; ++r) {
      int n = qr[qb] + 4 * g + r;
      bf16_t* op = O + (size_t)(b * 2048 + n) * 4096 + h * 128;
#pragma unroll
      for (int nb = 0; nb < 8; ++nb) op[nb * 16 + ci] = (bf16_t)(o[qb][nb][r] * lv[r]);
    }
  }
}

extern "C" void kernel_launch(void* const* d_in, const int* in_sizes, int n_in,
                              void* d_out, int out_size, void* d_ws, size_t ws_size,
                              hipStream_t stream) {
  (void)in_sizes; (void)n_in; (void)out_size; (void)ws_size;
  const float* X = (const float*)d_in[0];
  const int* pos = (const int*)d_in[1];
  const float* Wq = (const float*)d_in[2];
  const float* Wk = (const float*)d_in[3];
  const float* Wv = (const float*)d_in[4];
  const float* Wo = (const float*)d_in[5];
  float* out = (float*)d_out;

  char* w = (char*)d_ws;
  auto carve = [&](size_t bytes) {
    void* p = (void*)w;
    w += (bytes + 255) & ~(size_t)255;
    return p;
  };
  const size_t T = 4096;  // B*N tokens
  bf16_t* Xbf    = (bf16_t*)carve(T * 4096 * 2);
  bf16_t* WqkvT  = (bf16_t*)carve(6144ull * 4096 * 2);  // [Wq;Wk;Wv] transposed
  bf16_t* WoT    = (bf16_t*)carve(4096ull * 4096 * 2);
  bf16_t* QKVraw = (bf16_t*)carve(T * 6144 * 2);
  bf16_t* Kr     = (bf16_t*)carve(T * 1024 * 2);
  bf16_t* Vr     = (bf16_t*)carve(T * 1024 * 2);
  bf16_t* Obf    = (bf16_t*)carve(T * 4096 * 2);

  // fused prep: 4 weight transposes + X convert
  prep_all<<<12288, 256, 0, stream>>>(Wq, Wk, Wv, Wo, X, WqkvT, WoT, Xbf,
                                      (int)(T * 4096 / 4));

  // fused QKV projection: [4096 tokens][6144], 16 x 32 tiles of 256x192 = 512 blocks
  gemm8qkv<<<512, 512, 0, stream>>>(Xbf, WqkvT, QKVraw, 6144, 4096);

  // RoPE K + pack V (Q roped in attn)
  rope_kv<<<(int)(T * 8 / 8), 256, 0, stream>>>(QKVraw, pos, Kr, Vr);

  attn_kernel<<<dim3(8, 64), 512, 0, stream>>>(QKVraw, Kr, Vr, pos, Obf);

  // O projection: 16x16 tiles of 256^2 = 256 blocks (1 exact round)
  gemm8o<0><<<256, 512, 0, stream>>>(Obf, WoT, out, 4096, 4096);
}

// Round 18
// 502.900 us; speedup vs baseline: 1.0060x; 1.0060x over previous
//
#include <hip/hip_runtime.h>
#include <hip/hip_bf16.h>

typedef __bf16 bf16_t;
typedef float  f32x4  __attribute__((ext_vector_type(4)));
typedef bf16_t bf16x2 __attribute__((ext_vector_type(2)));
typedef bf16_t bf16x4 __attribute__((ext_vector_type(4)));
typedef bf16_t bf16x8 __attribute__((ext_vector_type(8)));

#define MFMA16(a, b, c) __builtin_amdgcn_mfma_f32_16x16x32_bf16((a), (b), (c), 0, 0, 0)

#define GLOAD_LDS16(g, l)                                                              \
  __builtin_amdgcn_global_load_lds((const __attribute__((address_space(1))) void*)(g), \
                                   (__attribute__((address_space(3))) void*)(l), 16, 0, 0)

#define BARRIER    __builtin_amdgcn_s_barrier()
#define WAIT_LGKM0 asm volatile("s_waitcnt lgkmcnt(0)" ::: "memory")
#define WAIT_LGKM8 asm volatile("s_waitcnt lgkmcnt(8)" ::: "memory")
#define WAIT_VM3   asm volatile("s_waitcnt vmcnt(3)" ::: "memory")
#define WAIT_VM4   asm volatile("s_waitcnt vmcnt(4)" ::: "memory")
#define WAIT_VM0   asm volatile("s_waitcnt vmcnt(0)" ::: "memory")

// ------- fused prep: 4 weight transposes + X f32->bf16 convert (one launch) -------
__global__ __launch_bounds__(256) void prep_all(const float* __restrict__ Wq,
                                                const float* __restrict__ Wk,
                                                const float* __restrict__ Wv,
                                                const float* __restrict__ Wo,
                                                const float* __restrict__ X,
                                                bf16_t* __restrict__ WqkvT,
                                                bf16_t* __restrict__ WoT,
                                                bf16_t* __restrict__ Xbf,
                                                int n4) {
  const int bid = blockIdx.x;
  if (bid >= 10240) {
    int stride = 2048 * 256;
    for (int i = (bid - 10240) * 256 + threadIdx.x; i < n4; i += stride) {
      f32x4 v = ((const f32x4*)X)[i];
      bf16x4 o;
#pragma unroll
      for (int j = 0; j < 4; ++j) o[j] = (bf16_t)v[j];
      ((bf16x4*)Xbf)[i] = o;
    }
    return;
  }
  __shared__ float t[64][65];
  const float* in;
  bf16_t* out;
  int C, cx, cy;
  if (bid < 4096) {
    in = Wq; out = WqkvT; C = 4096; cx = bid & 63; cy = bid >> 6;
  } else if (bid < 5120) {
    int tt = bid - 4096;
    in = Wk; out = WqkvT + 4096ull * 4096; C = 1024; cx = tt & 15; cy = tt >> 4;
  } else if (bid < 6144) {
    int tt = bid - 5120;
    in = Wv; out = WqkvT + 5120ull * 4096; C = 1024; cx = tt & 15; cy = tt >> 4;
  } else {
    int tt = bid - 6144;
    in = Wo; out = WoT; C = 4096; cx = tt & 63; cy = tt >> 6;
  }
  const int R = 4096;  // K dim (output stride)
  int tr0 = cy * 64, tc0 = cx * 64;
  int tx = threadIdx.x & 15, ty = threadIdx.x >> 4;
#pragma unroll
  for (int i = 0; i < 4; ++i) {
    f32x4 v = *(const f32x4*)(in + (size_t)(tr0 + ty + 16 * i) * C + tc0 + tx * 4);
#pragma unroll
    for (int j = 0; j < 4; ++j) t[ty + 16 * i][tx * 4 + j] = v[j];
  }
  __syncthreads();
#pragma unroll
  for (int i = 0; i < 4; ++i) {
    bf16x4 o4;
#pragma unroll
    for (int j = 0; j < 4; ++j) o4[j] = (bf16_t)t[tx * 4 + j][ty + 16 * i];
    *(bf16x4*)(out + (size_t)(tc0 + ty + 16 * i) * R + tr0 + tx * 4) = o4;
  }
}

// ================= 256x256 8-phase GEMM, 16x16x32 (O-projection) =================
// XCD 2-D supertile: 8 chunks of 4m x 8n (grid 16x16).
#define LDB8(bf)                                                                         \
  {                                                                                      \
    const int sb_ = bBase0 + (bf)*16384;                                                 \
    _Pragma("unroll") for (int nf = 0; nf < 4; ++nf) {                                   \
      int row_ = brow0 + nf * 16 + ci;                                                   \
      _Pragma("unroll") for (int ks = 0; ks < 2; ++ks)                                   \
          b[nf][ks] = *(const bf16x8*)&lds[sb_ + row_ * 64 + ((ks * 32 + g * 8) ^ co)];  \
    }                                                                                    \
  }

#define LDA4(bf, q)                                                                      \
  {                                                                                      \
    const int sb_ = aBase0 + (bf)*16384;                                                 \
    _Pragma("unroll") for (int j = 0; j < 2; ++j) {                                      \
      int row_ = ((q)*2 + j) * 16 + ci;                                                  \
      _Pragma("unroll") for (int ks = 0; ks < 2; ++ks)                                   \
          a[j][ks] = *(const bf16x8*)&lds[sb_ + row_ * 64 + ((ks * 32 + g * 8) ^ co)];   \
    }                                                                                    \
  }

#define MMQ(q)                                                                           \
  {                                                                                      \
    __builtin_amdgcn_s_setprio(1);                                                       \
    _Pragma("unroll") for (int j = 0; j < 2; ++j)                                        \
        _Pragma("unroll") for (int nf = 0; nf < 4; ++nf)                                 \
            _Pragma("unroll") for (int ks = 0; ks < 2; ++ks)                             \
                acc[(q)*2 + j][nf] = MFMA16(a[j][ks], b[nf][ks], acc[(q)*2 + j][nf]);    \
    __builtin_amdgcn_s_setprio(0);                                                       \
  }

template <int WRITE_BF16>
__global__ __launch_bounds__(512) void gemm8o(const bf16_t* __restrict__ A,
                                              const bf16_t* __restrict__ Bt,
                                              void* __restrict__ Cv,
                                              int N, int K) {
  __shared__ alignas(16) bf16_t lds[65536];  // A: [0,32768), B: [32768,65536)
  const int tid = threadIdx.x;
  const int lane = tid & 63, w = tid >> 6;
  const int wr = w >> 2, wc = w & 3;  // 2 M-waves x 4 N-waves
  const int g = lane >> 4, ci = lane & 15;
  const int c = (int)blockIdx.x & 7, ii = (int)blockIdx.x >> 3;
  const int m0 = ((c >> 1) * 4 + (ii >> 3)) * 256;
  const int n0 = ((c & 1) * 8 + (ii & 7)) * 256;
  const int ksw = ((lane & 7) ^ (lane >> 3)) << 3;
  const int aBase0 = wr * 8192;
  const int bBase0 = 32768 + (wc >> 1) * 8192;
  const int brow0 = (wc & 1) * 64;
  const int co = (ci & 7) << 3;

  const bf16_t* As[2] = {A + (size_t)m0 * K, A + (size_t)(m0 + 128) * K};
  const bf16_t* Bs[2] = {Bt + (size_t)n0 * K, Bt + (size_t)(n0 + 128) * K};

  auto stage = [&](const bf16_t* src, int kk, int ldsbase) {  // 128 rows x 64 k
#pragma unroll
    for (int j = 0; j < 2; ++j)
      GLOAD_LDS16(src + (size_t)(j * 64 + w * 8 + (lane >> 3)) * K + kk + ksw,
                  (char*)&lds[ldsbase + (j * 64 + w * 8) * 64]);
  };

  bf16x8 a[2][2], b[4][2];
  f32x4 acc[8][4];
#pragma unroll
  for (int mf = 0; mf < 8; ++mf)
#pragma unroll
    for (int nf = 0; nf < 4; ++nf) acc[mf][nf] = f32x4{0.f, 0.f, 0.f, 0.f};

  stage(As[0], 0, 0);
  stage(As[1], 0, 8192);
  stage(Bs[0], 0, 32768);
  stage(Bs[1], 0, 40960);
  stage(Bs[0], 64, 49152);
  stage(Bs[1], 64, 57344);
  WAIT_VM4;
  BARRIER;

  const int NT2 = K >> 7;
  for (int i = 0; i < NT2; ++i) {
    const int keb = i << 7;
    const int kA1 = keb + 64;
    int e2 = keb + 128;
    if (e2 > K - 64) e2 = K - 64;
    int o2 = keb + 192;
    if (o2 > K - 64) o2 = K - 64;
    LDA4(0, 0) LDB8(0)
    stage(As[0], kA1, 16384);
    WAIT_LGKM8;
    BARRIER; WAIT_LGKM0;
    MMQ(0)
    BARRIER;
    LDA4(0, 1)
    stage(As[1], kA1, 24576);
    BARRIER; WAIT_LGKM0;
    MMQ(1)
    BARRIER;
    LDA4(0, 2)
    stage(Bs[0], e2, 32768);
    BARRIER; WAIT_LGKM0;
    MMQ(2)
    BARRIER;
    LDA4(0, 3)
    stage(Bs[1], e2, 40960);
    BARRIER; WAIT_LGKM0;
    MMQ(3)
    WAIT_VM4;
    BARRIER;
    LDA4(1, 0) LDB8(1)
    stage(As[0], e2, 0);
    WAIT_LGKM8;
    BARRIER; WAIT_LGKM0;
    MMQ(0)
    BARRIER;
    LDA4(1, 1)
    stage(As[1], e2, 8192);
    BARRIER; WAIT_LGKM0;
    MMQ(1)
    BARRIER;
    LDA4(1, 2)
    stage(Bs[0], o2, 49152);
    BARRIER; WAIT_LGKM0;
    MMQ(2)
    BARRIER;
    LDA4(1, 3)
    stage(Bs[1], o2, 57344);
    BARRIER; WAIT_LGKM0;
    MMQ(3)
    WAIT_VM4;
    BARRIER;
  }
  WAIT_VM0;

#pragma unroll
  for (int mf = 0; mf < 8; ++mf) {
#pragma unroll
    for (int nf = 0; nf < 4; ++nf) {
      int grow = m0 + wr * 128 + mf * 16 + g * 4;
      int gcol = n0 + wc * 64 + nf * 16 + ci;
#pragma unroll
      for (int r = 0; r < 4; ++r) {
        if (WRITE_BF16)
          ((bf16_t*)Cv)[(size_t)(grow + r) * N + gcol] = (bf16_t)acc[mf][nf][r];
        else
          ((float*)Cv)[(size_t)(grow + r) * N + gcol] = acc[mf][nf][r];
      }
    }
  }
}

// ================= 256x192 8-phase GEMM, 16x16x32 (QKV) =================
// XCD 2-D supertile: 8 chunks of 8m x 8n (grid 16x32).
#define QLDB12(bf)                                                                        \
  {                                                                                       \
    const int sb_ = 32768 + (bf)*12288;                                                   \
    _Pragma("unroll") for (int nf = 0; nf < 6; ++nf) {                                    \
      int row_ = wc * 96 + nf * 16 + ci;                                                  \
      _Pragma("unroll") for (int ks = 0; ks < 2; ++ks)                                    \
          b[nf][ks] = *(const bf16x8*)&lds[sb_ + row_ * 64 + ((ks * 32 + g * 8) ^ co)];   \
    }                                                                                     \
  }

#define QLDA2(bf, q)                                                                      \
  {                                                                                       \
    const int sb_ = (bf)*16384;                                                           \
    const int row_ = wr * 64 + (q)*16 + ci;                                               \
    _Pragma("unroll") for (int ks = 0; ks < 2; ++ks)                                      \
        a[ks] = *(const bf16x8*)&lds[sb_ + row_ * 64 + ((ks * 32 + g * 8) ^ co)];         \
  }

#define QMMQ(q)                                                                           \
  {                                                                                       \
    __builtin_amdgcn_s_setprio(1);                                                        \
    _Pragma("unroll") for (int nf = 0; nf < 6; ++nf)                                      \
        _Pragma("unroll") for (int ks = 0; ks < 2; ++ks)                                  \
            acc[q][nf] = MFMA16(a[ks], b[nf][ks], acc[q][nf]);                            \
    __builtin_amdgcn_s_setprio(0);                                                        \
  }

__global__ __launch_bounds__(512) void gemm8qkv(const bf16_t* __restrict__ A,
                                                const bf16_t* __restrict__ Bt,
                                                bf16_t* __restrict__ C,
                                                int N, int K) {
  __shared__ alignas(16) bf16_t lds[57344];
  const int tid = threadIdx.x;
  const int lane = tid & 63, w = tid >> 6;
  const int wr = w >> 1, wc = w & 1;  // 4 M-waves x 2 N-waves
  const int g = lane >> 4, ci = lane & 15;
  const int c = (int)blockIdx.x & 7, ii = (int)blockIdx.x >> 3;
  const int m0 = ((c >> 2) * 8 + (ii >> 3)) * 256;
  const int n0 = ((c & 3) * 8 + (ii & 7)) * 192;
  const int ksw = ((lane & 7) ^ (lane >> 3)) << 3;
  const int co = (ci & 7) << 3;

  const bf16_t* Ar[4] = {A + (size_t)m0 * K, A + (size_t)(m0 + 64) * K,
                         A + (size_t)(m0 + 128) * K, A + (size_t)(m0 + 192) * K};
  const bf16_t* Br[3] = {Bt + (size_t)n0 * K, Bt + (size_t)(n0 + 64) * K,
                         Bt + (size_t)(n0 + 128) * K};

  auto stage64 = [&](const bf16_t* src, int kk, int ldsbase) {  // 64 rows x 64 k
    GLOAD_LDS16(src + (size_t)(w * 8 + (lane >> 3)) * K + kk + ksw,
                (char*)&lds[ldsbase + w * 512]);
  };

  bf16x8 a[2], b[6][2];
  f32x4 acc[4][6];
#pragma unroll
  for (int mf = 0; mf < 4; ++mf)
#pragma unroll
    for (int nf = 0; nf < 6; ++nf) acc[mf][nf] = f32x4{0.f, 0.f, 0.f, 0.f};

#pragma unroll
  for (int c2 = 0; c2 < 4; ++c2) stage64(Ar[c2], 0, c2 * 4096);
#pragma unroll
  for (int c2 = 0; c2 < 3; ++c2) stage64(Br[c2], 0, 32768 + c2 * 4096);
#pragma unroll
  for (int c2 = 0; c2 < 3; ++c2) stage64(Br[c2], 64, 45056 + c2 * 4096);
  WAIT_VM3;
  BARRIER;

  const int NT2 = K >> 7;
  for (int i = 0; i < NT2; ++i) {
    const int keb = i << 7;
    const int kA1 = keb + 64;
    int e2 = keb + 128;
    if (e2 > K - 64) e2 = K - 64;
    int o2 = keb + 192;
    if (o2 > K - 64) o2 = K - 64;
    QLDA2(0, 0) QLDB12(0)
    stage64(Ar[0], kA1, 16384);
    stage64(Ar[1], kA1, 16384 + 4096);
    WAIT_LGKM8;
    BARRIER; WAIT_LGKM0;
    QMMQ(0)
    BARRIER;
    QLDA2(0, 1)
    stage64(Ar[2], kA1, 16384 + 8192);
    stage64(Ar[3], kA1, 16384 + 12288);
    BARRIER; WAIT_LGKM0;
    QMMQ(1)
    BARRIER;
    QLDA2(0, 2)
    stage64(Br[0], e2, 32768);
    stage64(Br[1], e2, 32768 + 4096);
    BARRIER; WAIT_LGKM0;
    QMMQ(2)
    BARRIER;
    QLDA2(0, 3)
    stage64(Br[2], e2, 32768 + 8192);
    BARRIER; WAIT_LGKM0;
    QMMQ(3)
    WAIT_VM3;
    BARRIER;
    QLDA2(1, 0) QLDB12(1)
    stage64(Ar[0], e2, 0);
    stage64(Ar[1], e2, 4096);
    WAIT_LGKM8;
    BARRIER; WAIT_LGKM0;
    QMMQ(0)
    BARRIER;
    QLDA2(1, 1)
    stage64(Ar[2], e2, 8192);
    stage64(Ar[3], e2, 12288);
    BARRIER; WAIT_LGKM0;
    QMMQ(1)
    BARRIER;
    QLDA2(1, 2)
    stage64(Br[0], o2, 45056);
    stage64(Br[1], o2, 45056 + 4096);
    BARRIER; WAIT_LGKM0;
    QMMQ(2)
    BARRIER;
    QLDA2(1, 3)
    stage64(Br[2], o2, 45056 + 8192);
    BARRIER; WAIT_LGKM0;
    QMMQ(3)
    WAIT_VM3;
    BARRIER;
  }
  WAIT_VM0;

#pragma unroll
  for (int mf = 0; mf < 4; ++mf) {
#pragma unroll
    for (int nf = 0; nf < 6; ++nf) {
      int grow = m0 + wr * 64 + mf * 16 + g * 4;
      int gcol = n0 + wc * 96 + nf * 16 + ci;
#pragma unroll
      for (int r = 0; r < 4; ++r)
        C[(size_t)(grow + r) * N + gcol] = (bf16_t)acc[mf][nf][r];
    }
  }
}

// ------------- RoPE K + pack V: QKV [token][6144] -> Kr, Vr [B,KVH,N,D] -------------
__global__ __launch_bounds__(256) void rope_kv(const bf16_t* __restrict__ QKV,
                                               const int* __restrict__ pos,
                                               bf16_t* __restrict__ Kr,
                                               bf16_t* __restrict__ Vr) {
  int unit = blockIdx.x * 8 + (threadIdx.x >> 5);  // token*8 + kvh
  int l = threadIdx.x & 31;
  int token = unit >> 3, kvh = unit & 7;
  int b = token >> 11, n = token & 2047;
  const bf16_t* base = QKV + (size_t)token * 6144;
  // K rope
  {
    const bf16_t* src = base + 4096 + kvh * 128;
    bf16_t* dst = Kr + ((size_t)(b * 8 + kvh) * 2048 + n) * 128;
    float p = (float)pos[token];
    float a0 = p * exp2f(-(float)(2 * l) * 0.20762050593045702f);
    float a1 = p * exp2f(-(float)(2 * l + 1) * 0.20762050593045702f);
    float sn0, cs0, sn1, cs1;
    sincosf(a0, &sn0, &cs0);
    sincosf(a1, &sn1, &cs1);
    bf16x2 x0 = *(const bf16x2*)(src + 2 * l);
    bf16x2 x1 = *(const bf16x2*)(src + 64 + 2 * l);
    bf16x2 o0, o1;
    o0[0] = (bf16_t)((float)x0[0] * cs0 - (float)x1[0] * sn0);
    o0[1] = (bf16_t)((float)x0[1] * cs1 - (float)x1[1] * sn1);
    o1[0] = (bf16_t)((float)x1[0] * cs0 + (float)x0[0] * sn0);
    o1[1] = (bf16_t)((float)x1[1] * cs1 + (float)x0[1] * sn1);
    *(bf16x2*)(dst + 2 * l) = o0;
    *(bf16x2*)(dst + 64 + 2 * l) = o1;
  }
  // V pack
  {
    const bf16_t* src = base + 5120 + kvh * 128;
    bf16_t* dst = Vr + ((size_t)(b * 8 + kvh) * 2048 + n) * 128;
    *(bf16x4*)(dst + 4 * l) = *(const bf16x4*)(src + 4 * l);
  }
}

// ---------------- flash attention: r16 version (best measured) ----------------
__global__ __launch_bounds__(512) void attn_kernel(const bf16_t* __restrict__ QKV,
                                                   const bf16_t* __restrict__ K,
                                                   const bf16_t* __restrict__ V,
                                                   const int* __restrict__ pos,
                                                   bf16_t* __restrict__ O) {
  const float scale2 = 0.12751743f;  // (1/sqrt(128)) * log2(e)
  __shared__ alignas(16) bf16_t Kl[64 * 128];    // swizzled [kv][d] (16K)
  __shared__ alignas(16) bf16_t Vt[128 * 64];    // swizzled [d][kv] (16K)
  __shared__ alignas(16) bf16_t Pl[8][32 * 64];  // per-wave swizzled [q][kv] (32K)
  const int tid = threadIdx.x;
  const int lane = tid & 63, w = tid >> 6;
  const int g = lane >> 4, ci = lane & 15;
  const int hb = blockIdx.y;  // b*32 + h
  const int b = hb >> 5, h = hb & 31, kvh = h >> 2;
  const int p = blockIdx.x;  // pair index 0..7
  const int qtB = 15 - p;
  const int qr[2] = {p * 128 + w * 16, qtB * 128 + w * 16};
  const bf16_t* Kh = K + (size_t)(b * 8 + kvh) * 2048 * 128;
  const bf16_t* Vh = V + (size_t)(b * 8 + kvh) * 2048 * 128;

  // Q load + in-register RoPE + pre-scale by scale2 (once per block)
  bf16x8 bq[2][4];
#pragma unroll
  for (int qb = 0; qb < 2; ++qb) {
    const int n = qr[qb] + ci;
    const bf16_t* qp = QKV + (size_t)(b * 2048 + n) * 6144 + h * 128;
    bf16x8 raw[4];
#pragma unroll
    for (int ks = 0; ks < 4; ++ks) raw[ks] = *(const bf16x8*)(qp + ks * 32 + g * 8);
    float ppos = (float)pos[b * 2048 + n];
#pragma unroll
    for (int k2 = 0; k2 < 2; ++k2)
#pragma unroll
      for (int j = 0; j < 8; ++j) {
        int d = k2 * 32 + g * 8 + j;
        float ang = ppos * exp2f(-(float)d * 0.20762050593045702f);
        float sn, cs;
        sincosf(ang, &sn, &cs);
        float x0 = (float)raw[k2][j], x1 = (float)raw[k2 + 2][j];
        bq[qb][k2][j] = (bf16_t)((x0 * cs - x1 * sn) * scale2);
        bq[qb][k2 + 2][j] = (bf16_t)((x1 * cs + x0 * sn) * scale2);
      }
  }

  f32x4 o[2][8];
#pragma unroll
  for (int qb = 0; qb < 2; ++qb)
#pragma unroll
    for (int nb = 0; nb < 8; ++nb) o[qb][nb] = f32x4{0.f, 0.f, 0.f, 0.f};
  float mrow[2] = {-1e30f, -1e30f};
  float lrow[2] = {0.f, 0.f};

  // T14 reg-staged K/V
  bf16x8 kreg[2];
  bf16x4 rv[4];
  const int kq = tid >> 5, dq = tid & 31;
  auto loadKV = [&](int kv0) {
#pragma unroll
    for (int i = 0; i < 2; ++i) {
      int c = tid + i * 512;
      kreg[i] = *(const bf16x8*)(Kh + (size_t)(kv0 + (c >> 4)) * 128 + (c & 15) * 8);
    }
#pragma unroll
    for (int rr = 0; rr < 4; ++rr)
      rv[rr] = *(const bf16x4*)(Vh + (size_t)(kv0 + kq * 4 + rr) * 128 + dq * 4);
  };
  auto writeKV = [&]() {
#pragma unroll
    for (int i = 0; i < 2; ++i) {
      int c = tid + i * 512;
      int row = c >> 4, kc = (c & 15) * 8;
      int sw = ((row ^ (row >> 3)) & 7) << 4;
      *(bf16x8*)((char*)Kl + row * 256 + ((kc * 2) ^ sw)) = kreg[i];
    }
#pragma unroll
    for (int jj = 0; jj < 4; ++jj) {
      int d = dq * 4 + jj;
      bf16x4 cv;
#pragma unroll
      for (int rr = 0; rr < 4; ++rr) cv[rr] = rv[rr][jj];
      int sw = ((d ^ (d >> 3)) & 7) << 4;
      *(bf16x4*)((char*)Vt + d * 128 + ((kq * 8) ^ sw)) = cv;
    }
  };

  const int nt = (qtB + 1) * 2;
  loadKV(0);
  for (int t = 0; t < nt; ++t) {
    const int kv0 = t * 64;
    __syncthreads();
    writeKV();
    __syncthreads();
    if (t + 1 < nt) loadKV(kv0 + 64);

    bool act[2] = {kv0 <= qr[0] + 15, kv0 <= qr[1] + 15};
#pragma unroll
    for (int qb = 0; qb < 2; ++qb) {
      if (!act[qb]) continue;
      f32x4 st[4];
#pragma unroll
      for (int kvb = 0; kvb < 4; ++kvb) st[kvb] = f32x4{0.f, 0.f, 0.f, 0.f};
      __builtin_amdgcn_s_setprio(1);
#pragma unroll
      for (int kvb = 0; kvb < 4; ++kvb) {
        int row = kvb * 16 + ci;
        int sw = ((row ^ (row >> 3)) & 7) << 4;
#pragma unroll
        for (int ks = 0; ks < 4; ++ks) {
          bf16x8 ak = *(const bf16x8*)((char*)Kl + row * 256 + ((ks * 64 + g * 16) ^ sw));
          st[kvb] = MFMA16(ak, bq[qb][ks], st[kvb]);
        }
      }
      __builtin_amdgcn_s_setprio(0);
      const int q = qr[qb] + ci;
      float pm = -1e30f;
      if (kv0 + 63 > qr[qb]) {  // diagonal tile: causal mask (wave-uniform branch)
#pragma unroll
        for (int kvb = 0; kvb < 4; ++kvb)
#pragma unroll
          for (int r = 0; r < 4; ++r) {
            float v = st[kvb][r];  // Q pre-scaled
            if (kv0 + kvb * 16 + 4 * g + r > q) v = -1e30f;
            st[kvb][r] = v;
            pm = fmaxf(pm, v);
          }
      } else {
#pragma unroll
        for (int kvb = 0; kvb < 4; ++kvb)
#pragma unroll
          for (int r = 0; r < 4; ++r) pm = fmaxf(pm, st[kvb][r]);
      }
      pm = fmaxf(pm, __shfl_xor(pm, 16));
      pm = fmaxf(pm, __shfl_xor(pm, 32));
      // T13 defer-max (log2 domain threshold ~ 8*log2e)
      const bool nskip = !__all((int)(pm <= mrow[qb] + 11.5f));
      const float mold = mrow[qb];
      float mnew = mold;
      float fs = 1.0f;
      if (nskip) {
        mnew = fmaxf(mold, pm);
        fs = exp2f(mold - mnew);
        mrow[qb] = mnew;
      }
      float ps = 0.f;
#pragma unroll
      for (int kvb = 0; kvb < 4; ++kvb)
#pragma unroll
        for (int r = 0; r < 4; ++r) {
          st[kvb][r] = exp2f(st[kvb][r] - mnew);
          ps += st[kvb][r];
        }
      ps += __shfl_xor(ps, 16);
      ps += __shfl_xor(ps, 32);
      lrow[qb] = (nskip ? lrow[qb] * fs : lrow[qb]) + ps;
      int prow = qb * 16 + ci;
      int swp = ((prow ^ (prow >> 3)) & 7) << 4;
#pragma unroll
      for (int kvb = 0; kvb < 4; ++kvb) {
        bf16x4 pk;
#pragma unroll
        for (int r = 0; r < 4; ++r) pk[r] = (bf16_t)st[kvb][r];
        *(bf16x4*)((char*)&Pl[w][0] + prow * 128 + (((kvb * 16 + 4 * g) * 2) ^ swp)) = pk;
      }
      if (nskip) {
        float fo[4];
#pragma unroll
        for (int r = 0; r < 4; ++r) fo[r] = __shfl(fs, 4 * g + r);
#pragma unroll
        for (int nb = 0; nb < 8; ++nb)
#pragma unroll
          for (int r = 0; r < 4; ++r) o[qb][nb][r] *= fo[r];
      }
    }
    bf16x8 pa[2][2];
#pragma unroll
    for (int qb = 0; qb < 2; ++qb) {
      if (!act[qb]) continue;
      int prow = qb * 16 + ci;
      int swp = ((prow ^ (prow >> 3)) & 7) << 4;
#pragma unroll
      for (int ks = 0; ks < 2; ++ks)
        pa[qb][ks] = *(const bf16x8*)((char*)&Pl[w][0] + prow * 128 + ((ks * 64 + g * 16) ^ swp));
    }
    __builtin_amdgcn_s_setprio(1);
#pragma unroll
    for (int nb = 0; nb < 8; ++nb) {
      int d = nb * 16 + ci;
      int sw = ((d ^ (d >> 3)) & 7) << 4;
      bf16x8 bv0 = *(const bf16x8*)((char*)Vt + d * 128 + ((g * 16) ^ sw));
      bf16x8 bv1 = *(const bf16x8*)((char*)Vt + d * 128 + ((64 + g * 16) ^ sw));
#pragma unroll
      for (int qb = 0; qb < 2; ++qb) {
        if (!act[qb]) continue;
        o[qb][nb] = MFMA16(pa[qb][0], bv0, o[qb][nb]);
        o[qb][nb] = MFMA16(pa[qb][1], bv1, o[qb][nb]);
      }
    }
    __builtin_amdgcn_s_setprio(0);
  }
#pragma unroll
  for (int qb = 0; qb < 2; ++qb) {
    float linv = 1.0f / lrow[qb];
    float lv[4];
#pragma unroll
    for (int r = 0; r < 4; ++r) lv[r] = __shfl(linv, 4 * g + r);
#pragma unroll
    for (int r = 0; r < 4; ++r) {
      int n = qr[qb] + 4 * g + r;
      bf16_t* op = O + (size_t)(b * 2048 + n) * 4096 + h * 128;
#pragma unroll
      for (int nb = 0; nb < 8; ++nb) op[nb * 16 + ci] = (bf16_t)(o[qb][nb][r] * lv[r]);
    }
  }
}

extern "C" void kernel_launch(void* const* d_in, const int* in_sizes, int n_in,
                              void* d_out, int out_size, void* d_ws, size_t ws_size,
                              hipStream_t stream) {
  (void)in_sizes; (void)n_in; (void)out_size; (void)ws_size;
  const float* X = (const float*)d_in[0];
  const int* pos = (const int*)d_in[1];
  const float* Wq = (const float*)d_in[2];
  const float* Wk = (const float*)d_in[3];
  const float* Wv = (const float*)d_in[4];
  const float* Wo = (const float*)d_in[5];
  float* out = (float*)d_out;

  char* w = (char*)d_ws;
  auto carve = [&](size_t bytes) {
    void* p = (void*)w;
    w += (bytes + 255) & ~(size_t)255;
    return p;
  };
  const size_t T = 4096;  // B*N tokens
  bf16_t* Xbf    = (bf16_t*)carve(T * 4096 * 2);
  bf16_t* WqkvT  = (bf16_t*)carve(6144ull * 4096 * 2);  // [Wq;Wk;Wv] transposed
  bf16_t* WoT    = (bf16_t*)carve(4096ull * 4096 * 2);
  bf16_t* QKVraw = (bf16_t*)carve(T * 6144 * 2);
  bf16_t* Kr     = (bf16_t*)carve(T * 1024 * 2);
  bf16_t* Vr     = (bf16_t*)carve(T * 1024 * 2);
  bf16_t* Obf    = (bf16_t*)carve(T * 4096 * 2);

  // fused prep: 4 weight transposes + X convert
  prep_all<<<12288, 256, 0, stream>>>(Wq, Wk, Wv, Wo, X, WqkvT, WoT, Xbf,
                                      (int)(T * 4096 / 4));

  // fused QKV projection: [4096 tokens][6144], 16 x 32 tiles of 256x192 = 512 blocks
  gemm8qkv<<<512, 512, 0, stream>>>(Xbf, WqkvT, QKVraw, 6144, 4096);

  // RoPE K + pack V (Q roped in attn)
  rope_kv<<<(int)(T * 8 / 8), 256, 0, stream>>>(QKVraw, pos, Kr, Vr);

  attn_kernel<<<dim3(8, 64), 512, 0, stream>>>(QKVraw, Kr, Vr, pos, Obf);

  // O projection: 16x16 tiles of 256^2 = 256 blocks (1 exact round)
  gemm8o<0><<<256, 512, 0, stream>>>(Obf, WoT, out, 4096, 4096);
}